// Round 8
// baseline (1404.842 us; speedup 1.0000x reference)
//
#include <hip/hip_runtime.h>
#include <hip/hip_bf16.h>
#include <hip/hip_fp16.h>
#include <math.h>

// ---------------- bucketed CSR build ----------------
// bucket = dst >> 8 (256 nodes/bucket). NB = ceil(N/256) <= 512.
// R21: sort key = (dstlocal, srcslice, rel), srcslice = min(src/NS, 7),
// NS = ceil(N/8). Slice s data (1.6MB xbb + 0.4MB kn) is gathered ONLY by
// blocks with blockIdx%8 == s, which land on XCD s (round-robin dispatch)
// -> slice stays resident in that XCD's 4MB L2 across all block generations.
// R13-R20 closed the case: gather throughput = per-CU MSHR cap (~16 lines)
// / avg miss latency; only latency is reducible, and only spatially
// (R19's temporal windowing decohered; coherent ceiling was 1.23x).
// rp3[node*8+s] = start of slice s within the node's csr row.

#define CSR_CHUNK 8192

__global__ void k_bhist(const int* __restrict__ dst, int* __restrict__ bcount,
                        int E, int NB) {
    __shared__ int h[512];
    int t = threadIdx.x;
    for (int i = t; i < NB; i += 256) h[i] = 0;
    __syncthreads();
    int e0 = blockIdx.x * CSR_CHUNK;
    int e1 = min(e0 + CSR_CHUNK, E);
    for (int i = e0 + t; i < e1; i += 256) atomicAdd(&h[dst[i] >> 8], 1);
    __syncthreads();
    for (int i = t; i < NB; i += 256) {
        int c = h[i];
        if (c) atomicAdd(&bcount[i], c);
    }
}

__global__ void k_bscan(const int* __restrict__ bcount, int* __restrict__ bstart,
                        int* __restrict__ gcur, int* __restrict__ rp3,
                        int NB, int N, int E) {
    __shared__ int s[512];
    int t = threadIdx.x;
    int v = (t < NB) ? bcount[t] : 0;
    s[t] = v;
    __syncthreads();
    for (int off = 1; off < 512; off <<= 1) {
        int a = (t >= off) ? s[t - off] : 0;
        __syncthreads();
        s[t] += a;
        __syncthreads();
    }
    int excl = s[t] - v;
    if (t < NB) {
        bstart[t] = excl;
        gcur[t] = excl;
    }
    if (t == 0) bstart[NB] = E;
    if (t < 8) rp3[(size_t)N * 8 + t] = E;   // end sentinel for node N-1 slice 7
}

// pass A: scatter packed edges grouped by bucket per block.
// pack: dstlocal(8) << 20 | rel(3) << 17 | src(17)
__global__ void k_bscatter(const int* __restrict__ src, const int* __restrict__ dst,
                           const int* __restrict__ et, int* __restrict__ gcur,
                           unsigned* __restrict__ ebuf, int E, int NB) {
    __shared__ int h[512];
    __shared__ int basearr[512];
    int t = threadIdx.x;
    for (int i = t; i < NB; i += 256) h[i] = 0;
    __syncthreads();
    int e0 = blockIdx.x * CSR_CHUNK;
    int e1 = min(e0 + CSR_CHUNK, E);
    for (int i = e0 + t; i < e1; i += 256) atomicAdd(&h[dst[i] >> 8], 1);
    __syncthreads();
    for (int i = t; i < NB; i += 256) {
        int c = h[i];
        basearr[i] = c ? atomicAdd(&gcur[i], c) : 0;
        h[i] = 0;
    }
    __syncthreads();
    for (int i = e0 + t; i < e1; i += 256) {
        int d = dst[i];
        int b = d >> 8;
        int off = atomicAdd(&h[b], 1);
        ebuf[basearr[b] + off] =
            ((unsigned)(d & 255) << 20) | ((unsigned)et[i] << 17) | (unsigned)src[i];
    }
}

// pass B: one block per bucket. 16384-bin (node, slice, rel) counting sort.
// In-place exclusive prefix + atomicAdd-cursor scatter (R19-verified pattern).
// Emits rp3[node*8+s]; csr entry keeps full pack (fallback needs dstlocal).
__global__ void k_bsort(const unsigned* __restrict__ ebuf, const int* __restrict__ bstart,
                        int* __restrict__ rp3, int* __restrict__ csr, int N, int NS) {
    __shared__ int lh[16384];
    __shared__ int ss[256];
    int b = blockIdx.x, t = threadIdx.x;
    int e0 = bstart[b], e1 = bstart[b + 1];
    for (int i = t; i < 16384; i += 256) lh[i] = 0;
    __syncthreads();
    for (int i = e0 + t; i < e1; i += 256) {
        unsigned u = ebuf[i];
        int dl = (u >> 20) & 255;
        int rel = (u >> 17) & 7;
        int w = min((int)(u & 0x1FFFF) / NS, 7);
        atomicAdd(&lh[dl * 64 + w * 8 + rel], 1);
    }
    __syncthreads();
    int s = 0;
#pragma unroll 1
    for (int k = 0; k < 64; k++) {
        int c = lh[t * 64 + k];
        lh[t * 64 + k] = s;
        s += c;
    }
    ss[t] = s;
    __syncthreads();
    for (int off = 1; off < 256; off <<= 1) {
        int a = (t >= off) ? ss[t - off] : 0;
        __syncthreads();
        ss[t] += a;
        __syncthreads();
    }
    int excl = ss[t] - s;
#pragma unroll 1
    for (int k = 0; k < 64; k++) lh[t * 64 + k] += excl;
    __syncthreads();
    int node = b * 256 + t;
    if (node < N) {
#pragma unroll
        for (int p2 = 0; p2 < 8; p2++)
            rp3[(size_t)node * 8 + p2] = e0 + lh[t * 64 + p2 * 8];
    }
    __syncthreads();   // all rp3 reads done before cursor mutation
    for (int i = e0 + t; i < e1; i += 256) {
        unsigned u = ebuf[i];
        int dl = (u >> 20) & 255;
        int rel = (u >> 17) & 7;
        int w = min((int)(u & 0x1FFFF) / NS, 7);
        int pos = e0 + atomicAdd(&lh[dl * 64 + w * 8 + rel], 1);
        csr[pos] = (int)u;
    }
}

// ---------------- weight prep ----------------

__global__ void k_wt2(const float* __restrict__ W, __hip_bfloat16* __restrict__ hi,
                      __hip_bfloat16* __restrict__ lo, int OUT, int total) {
    int t = blockIdx.x * blockDim.x + threadIdx.x;
    if (t < total) {
        int per = 64 * OUT;
        int r = t / per;
        int rem = t % per;
        int i = rem / OUT;
        int o = rem % OUT;
        float v = W[t];
        __hip_bfloat16 h = __float2bfloat16(v);
        __hip_bfloat16 l = __float2bfloat16(v - __bfloat162float(h));
        size_t idx = (size_t)o * 512 + i * 8 + r;
        hi[idx] = h;
        lo[idx] = l;
    }
}

__global__ void k_wqk(const float* W, const float* Qv, const float* Kv,
                      float* wq, float* wk, int OUT) {
    int t = blockIdx.x * blockDim.x + threadIdx.x;
    if (t < 8 * 64) {
        int r = t >> 6, i = t & 63;
        const float* wrow = W + ((size_t)r * 64 + i) * OUT;
        float a = 0.f, b = 0.f;
        for (int o = 0; o < OUT; o++) {
            float w = wrow[o];
            a += w * Qv[o];
            b += w * Kv[o];
        }
        wq[t] = a;
        wk[t] = b;
    }
}

// ---------------- q/k projection + bf16 table emit (layer 0 input) ----------------
__global__ __launch_bounds__(256) void k_qk2(
        const float* __restrict__ xin, const float* __restrict__ wq,
        const float* __restrict__ wk, float* __restrict__ qn,
        float* __restrict__ kn, unsigned short* __restrict__ xbb, int N) {
    __shared__ float xt[64][65];
    __shared__ float swq[8 * 65], swk[8 * 65];
    int t = threadIdx.x;
    int nb0 = blockIdx.x * 64;
    for (int i = t; i < 512; i += 256) {
        int r = i >> 6, c = i & 63;
        swq[r * 65 + c] = wq[i];
        swk[r * 65 + c] = wk[i];
    }
    for (int i = t; i < 1024; i += 256) {
        int ns = i >> 4;
        int c4 = i & 15;
        int n = nb0 + ns;
        float4 v = {0.f, 0.f, 0.f, 0.f};
        if (n < N) v = ((const float4*)xin)[(size_t)n * 16 + c4];
        xt[ns][c4 * 4 + 0] = v.x;
        xt[ns][c4 * 4 + 1] = v.y;
        xt[ns][c4 * 4 + 2] = v.z;
        xt[ns][c4 * 4 + 3] = v.w;
        if (n < N) {
            __hip_bfloat16 b0 = __float2bfloat16(v.x);
            __hip_bfloat16 b1 = __float2bfloat16(v.y);
            __hip_bfloat16 b2 = __float2bfloat16(v.z);
            __hip_bfloat16 b3 = __float2bfloat16(v.w);
            ushort4 o;
            o.x = *(unsigned short*)&b0;
            o.y = *(unsigned short*)&b1;
            o.z = *(unsigned short*)&b2;
            o.w = *(unsigned short*)&b3;
            *(ushort4*)(xbb + (size_t)n * 64 + c4 * 4) = o;
        }
    }
    __syncthreads();
#pragma unroll
    for (int g = t; g < 512; g += 256) {
        int ns = g >> 3, r = g & 7;
        int n = nb0 + ns;
        if (n < N) {
            float qa = 0.f, ka = 0.f;
#pragma unroll
            for (int i = 0; i < 64; i++) {
                float xv = xt[ns][i];
                qa += xv * swq[r * 65 + i];
                ka += xv * swk[r * 65 + i];
            }
            qn[(size_t)n * 8 + r] = qa;
            kn[(size_t)n * 8 + r] = ka;
        }
    }
}

#define ZSTR 520
#define EMAX 512

#define FLUSH8()                          \
    do {                                  \
        switch (currel) {                 \
            case 0: a0 += racc; break;    \
            case 1: a1 += racc; break;    \
            case 2: a2 += racc; break;    \
            case 3: a3 += racc; break;    \
            case 4: a4 += racc; break;    \
            case 5: a5 += racc; break;    \
            case 6: a6 += racc; break;    \
            case 7: a7 += racc; break;    \
        }                                 \
    } while (0)

// ---------------- R21: XCD-slice aggregation ----------------
// Block b: tile = b>>3 (16 dst nodes), slice = b&7 (== XCD id, round-robin).
// Gathers touch ONLY slice data (1.6MB xbb + 0.4MB kn) -> L2-resident on
// that XCD across all block generations -> ~200cy hits vs ~650 avg.
// Per (node, slice): merged attention+drain (R17 style) in clamp-padded
// groups of 4; LOCAL normalization (qout bounded by max|x| -> bf16/fp16
// safe); partial denom -> pden[slice][node]; GEMM per slice -> partial out
// qout.W -> pout[slice][node][OUT] fp16 (nontemporal). Exact reconstruction
// in k_fin: out = (sum_s pout_s * pden_s) / sum_s pden_s + bias.
template <int OUT>
__global__ __launch_bounds__(256) void k_agg(
        const int* __restrict__ rp3, const int* __restrict__ csr,
        const float* __restrict__ qn, const float* __restrict__ kn,
        const unsigned short* __restrict__ xb,
        const __hip_bfloat16* __restrict__ wthi,
        const __hip_bfloat16* __restrict__ wtlo,
        __half* __restrict__ pout, float* __restrict__ pden, int N) {
    using v8s = __attribute__((ext_vector_type(8))) short;
    using v4f = __attribute__((ext_vector_type(4))) float;
    __shared__ unsigned short zt[16 * ZSTR];
    int t = threadIdx.x;
    int wvu = __builtin_amdgcn_readfirstlane(t >> 6);
    int lane = t & 63;
    int b = blockIdx.x;
    int slice = b & 7;
    int nb0 = (b >> 3) * 16;

#pragma unroll 1
    for (int q = 0; q < 4; q++) {
        int nl = wvu * 4 + q;
        int wid = nb0 + nl;
        uint4 pack = {0u, 0u, 0u, 0u};
        if (wid < N) {                          // wave-uniform
            int r0 = rp3[(size_t)wid * 8 + slice];
            int r1 = (slice < 7) ? rp3[(size_t)wid * 8 + slice + 1]
                                 : rp3[(size_t)(wid + 1) * 8];
            int qvec = 0;
            if (lane < 8) qvec = ((const int*)qn)[wid * 8 + lane];
            float a0 = 0.f, a1 = 0.f, a2 = 0.f, a3 = 0.f;
            float a4 = 0.f, a5 = 0.f, a6 = 0.f, a7 = 0.f;
            float racc = 0.f, denom = 0.f;
            int currel = 0;
#pragma unroll 1
            for (int j = r0; j < r1; j += 4) {
                int pk[4];
                float kv[4];
                unsigned short xu[4];
#pragma unroll
                for (int u = 0; u < 4; u++) {
                    int ii = (j + u < r1) ? (j + u) : (r1 - 1);
                    pk[u] = csr[ii];            // uniform sequential
                }
#pragma unroll
                for (int u = 0; u < 4; u++)
                    kv[u] = kn[(size_t)(pk[u] & 0x1FFFF) * 8 + ((pk[u] >> 17) & 7)];
#pragma unroll
                for (int u = 0; u < 4; u++)
                    xu[u] = xb[(size_t)(pk[u] & 0x1FFFF) * 64 + lane];  // slice-L2-hot
#pragma unroll
                for (int u = 0; u < 4; u++) {
                    int rl = (pk[u] >> 17) & 7;
                    float qv = __uint_as_float(__builtin_amdgcn_readlane(qvec, rl));
                    float v = qv + kv[u];
                    v = fmaxf(v, 0.2f * v);     // leaky_relu 0.2
                    float tv = __expf(v);
                    if (j + u >= r1) tv = 0.f;  // pad slot
                    if (rl != currel) {         // uniform scalar branch
                        FLUSH8();
                        currel = rl;
                        racc = 0.f;
                    }
                    racc += tv * __uint_as_float(((unsigned)xu[u]) << 16);
                    denom += tv;
                }
            }
            FLUSH8();
            float inv = (denom > 0.f) ? 1.f / denom : 0.f;  // LOCAL normalize
            float av[8] = {a0, a1, a2, a3, a4, a5, a6, a7};
            unsigned short us[8];
#pragma unroll
            for (int r = 0; r < 8; r++) {
                __hip_bfloat16 bb = __float2bfloat16(av[r] * inv);
                us[r] = *(unsigned short*)&bb;
            }
            pack.x = (unsigned)us[0] | ((unsigned)us[1] << 16);
            pack.y = (unsigned)us[2] | ((unsigned)us[3] << 16);
            pack.z = (unsigned)us[4] | ((unsigned)us[5] << 16);
            pack.w = (unsigned)us[6] | ((unsigned)us[7] << 16);
            if (lane == 0) pden[(size_t)slice * N + wid] = denom;
        }
        *(uint4*)&zt[nl * ZSTR + lane * 8] = pack;  // zero for tail rows
    }
    __syncthreads();

    // per-slice GEMM -> partial out (fp16, nontemporal)
    int quad = lane >> 4;
    int l15 = lane & 15;
    int nt = wvu;
    if (nt * 16 < OUT) {
        const short* wh = (const short*)wthi;
        const short* wl = (const short*)wtlo;
        v4f acc = {0.f, 0.f, 0.f, 0.f};
#pragma unroll
        for (int k0 = 0; k0 < 512; k0 += 32) {
            int koff = k0 + quad * 8;
            v8s A = *(const v8s*)&zt[l15 * ZSTR + koff];
            v8s bh = *(const v8s*)(wh + (size_t)(nt * 16 + l15) * 512 + koff);
            v8s bl = *(const v8s*)(wl + (size_t)(nt * 16 + l15) * 512 + koff);
            acc = __builtin_amdgcn_mfma_f32_16x16x32_bf16(A, bh, acc, 0, 0, 0);
            acc = __builtin_amdgcn_mfma_f32_16x16x32_bf16(A, bl, acc, 0, 0, 0);
        }
#pragma unroll
        for (int g = 0; g < 4; g++) {
            int row = nb0 + quad * 4 + g;
            if (row < N) {
                __half hv = __float2half(acc[g]);
                __builtin_nontemporal_store(
                    *(short*)&hv,
                    (short*)(pout + ((size_t)slice * N + row) * OUT + nt * 16 + l15));
            }
        }
    }
}

// ---------------- R21 finalize: reduce 8 slices (+bias, relu) ----------------
// QK=true (layer 0): also emits xbb + qn/kn for layer 1 (k_qk2 deleted there).
template <int OUT, bool RELU, bool QK>
__global__ __launch_bounds__(256) void k_fin(
        const __half* __restrict__ pout, const float* __restrict__ pden,
        const float* __restrict__ bias, const float* __restrict__ wq,
        const float* __restrict__ wk, float* __restrict__ qn,
        float* __restrict__ kn, unsigned short* __restrict__ xbb,
        float* __restrict__ fout, int N) {
    __shared__ float xt[64][65];
    __shared__ float swq[8 * 65], swk[8 * 65];
    __shared__ float spd[64][9];
    int t = threadIdx.x;
    int nb0 = blockIdx.x * 64;
    if (QK) {
        for (int i = t; i < 512; i += 256) {
            int r = i >> 6, c = i & 63;
            swq[r * 65 + c] = wq[i];
            swk[r * 65 + c] = wk[i];
        }
    }
    for (int i = t; i < 512; i += 256) {
        int ns = i >> 3, s = i & 7;
        int n = nb0 + ns;
        spd[ns][s] = (n < N) ? pden[(size_t)s * N + n] : 0.f;
    }
    __syncthreads();
    if (t < 64) {
        float D = 0.f;
#pragma unroll
        for (int s = 0; s < 8; s++) D += spd[t][s];
        spd[t][8] = 1.f / (D + 1e-16f);
    }
    __syncthreads();
    constexpr int D4 = OUT / 4;
    for (int i = t; i < 64 * D4; i += 256) {
        int ns = i / D4, d4 = i % D4;
        int n = nb0 + ns;
        if (n < N) {
            float v[4] = {0.f, 0.f, 0.f, 0.f};
#pragma unroll
            for (int s = 0; s < 8; s++) {
                float w = spd[ns][s];
                const __half* pr = pout + ((size_t)s * N + n) * OUT + d4 * 4;
#pragma unroll
                for (int k = 0; k < 4; k++) v[k] += w * __half2float(pr[k]);
            }
            float inv = spd[ns][8];
#pragma unroll
            for (int k = 0; k < 4; k++) {
                float o = v[k] * inv + bias[d4 * 4 + k];
                if (RELU) o = fmaxf(o, 0.f);
                v[k] = o;
            }
            if (QK) {
#pragma unroll
                for (int k = 0; k < 4; k++) xt[ns][d4 * 4 + k] = v[k];
                __hip_bfloat16 b0 = __float2bfloat16(v[0]);
                __hip_bfloat16 b1 = __float2bfloat16(v[1]);
                __hip_bfloat16 b2 = __float2bfloat16(v[2]);
                __hip_bfloat16 b3 = __float2bfloat16(v[3]);
                ushort4 o4;
                o4.x = *(unsigned short*)&b0;
                o4.y = *(unsigned short*)&b1;
                o4.z = *(unsigned short*)&b2;
                o4.w = *(unsigned short*)&b3;
                *(ushort4*)(xbb + (size_t)n * 64 + d4 * 4) = o4;
            } else {
#pragma unroll
                for (int k = 0; k < 4; k++)
                    fout[(size_t)n * OUT + d4 * 4 + k] = v[k];
            }
        }
    }
    if (QK) {
        __syncthreads();
        for (int g = t; g < 512; g += 256) {
            int ns = g >> 3, r = g & 7;
            int n = nb0 + ns;
            if (n < N) {
                float qa = 0.f, ka = 0.f;
#pragma unroll
                for (int i2 = 0; i2 < 64; i2++) {
                    float xv = xt[ns][i2];
                    qa += xv * swq[r * 65 + i2];
                    ka += xv * swk[r * 65 + i2];
                }
                qn[(size_t)n * 8 + r] = qa;
                kn[(size_t)n * 8 + r] = ka;
            }
        }
    }
}

// ---------------- R20 fallback (ws-insufficient): random-gather fused ----------------
template <int OUT, bool RELU>
__global__ __launch_bounds__(256) void k_fused(
        const int* __restrict__ rp3, const int* __restrict__ csr,
        const float* __restrict__ qn, const float* __restrict__ kn,
        const unsigned short* __restrict__ xb,
        const __hip_bfloat16* __restrict__ wthi,
        const __hip_bfloat16* __restrict__ wtlo,
        const float* __restrict__ bias, float* __restrict__ xout, int N) {
    using v8s = __attribute__((ext_vector_type(8))) short;
    using v4f = __attribute__((ext_vector_type(4))) float;
    __shared__ unsigned short zt[16 * ZSTR];
    __shared__ uint2 s_rec[EMAX];
    __shared__ float s_q[128];
    int t = threadIdx.x;
    int wv = t >> 6;
    int lane = t & 63;
    int nb0 = blockIdx.x * 16;

    if (t < 128) {
        int nd = nb0 + (t >> 3);
        s_q[t] = (nd < N) ? qn[(size_t)nd * 8 + (t & 7)] : 0.f;
    }
    int e0 = rp3[(size_t)nb0 * 8];
    int eend = rp3[(size_t)min(nb0 + 16, N) * 8];
    int esz = eend - e0;
    __syncthreads();

    if (esz <= EMAX) {
        for (int i = t; i < esz; i += 256) {
            int pk = csr[e0 + i];
            int nl = (pk >> 20) & 15;
            int rel = (pk >> 17) & 7;
            int src = pk & 0x1FFFF;
            float v = s_q[nl * 8 + rel] + kn[(size_t)src * 8 + rel];
            v = (v >= 0.f) ? v : 0.2f * v;
            float tv = __expf(v);
            s_rec[i] = uint2{__float_as_uint(tv), (unsigned)pk};
        }
        __syncthreads();

#pragma unroll 1
        for (int q = 0; q < 4; q++) {
            int nl = wv * 4 + q;
            int wid = nb0 + nl;
            uint4 pack = {0u, 0u, 0u, 0u};
            if (wid < N) {
                int r0 = rp3[(size_t)wid * 8] - e0;
                int r1 = rp3[(size_t)(wid + 1) * 8] - e0;
                float a0 = 0.f, a1 = 0.f, a2 = 0.f, a3 = 0.f;
                float a4 = 0.f, a5 = 0.f, a6 = 0.f, a7 = 0.f;
                float racc = 0.f, denom = 0.f;
                int currel = 0;
#pragma unroll 1
                for (int j = r0; j < r1; j += 16) {
                    float tvv[16];
                    int pkk[16];
#pragma unroll
                    for (int u = 0; u < 16; u++) {
                        int ii = j + u;
                        bool ok = ii < r1;
                        ii = ok ? ii : (r1 - 1);
                        uint2 rc = s_rec[ii];
                        tvv[u] = __uint_as_float(
                            __builtin_amdgcn_readfirstlane((int)(ok ? rc.x : 0u)));
                        pkk[u] = __builtin_amdgcn_readfirstlane((int)rc.y);
                    }
                    unsigned short xu[16];
#pragma unroll
                    for (int u = 0; u < 16; u++)
                        xu[u] = xb[(size_t)(pkk[u] & 0x1FFFF) * 64 + lane];
#pragma unroll
                    for (int u = 0; u < 16; u++) {
                        int rl = (pkk[u] >> 17) & 7;
                        if (rl != currel) {
                            FLUSH8();
                            currel = rl;
                            racc = 0.f;
                        }
                        racc += tvv[u] * __uint_as_float(((unsigned)xu[u]) << 16);
                        denom += tvv[u];
                    }
                }
                FLUSH8();
                float inv = 1.f / (denom + 1e-16f);
                float av[8] = {a0, a1, a2, a3, a4, a5, a6, a7};
                unsigned short us[8];
#pragma unroll
                for (int r = 0; r < 8; r++) {
                    __hip_bfloat16 bb = __float2bfloat16(av[r] * inv);
                    us[r] = *(unsigned short*)&bb;
                }
                pack.x = (unsigned)us[0] | ((unsigned)us[1] << 16);
                pack.y = (unsigned)us[2] | ((unsigned)us[3] << 16);
                pack.z = (unsigned)us[4] | ((unsigned)us[5] << 16);
                pack.w = (unsigned)us[6] | ((unsigned)us[7] << 16);
            }
            *(uint4*)&zt[nl * ZSTR + lane * 8] = pack;
        }
    } else {
        for (int q = 0; q < 4; q++) {
            int nl = wv * 4 + q;
            int wid = nb0 + nl;
            uint4 pack = {0u, 0u, 0u, 0u};
            if (wid < N) {
                int r0 = rp3[(size_t)wid * 8], r1 = rp3[(size_t)(wid + 1) * 8];
                float qv = (lane < 8) ? qn[wid * 8 + lane] : 0.f;
                float denom = 0.f;
                float a0 = 0.f, a1 = 0.f, a2 = 0.f, a3 = 0.f;
                float a4 = 0.f, a5 = 0.f, a6 = 0.f, a7 = 0.f;
                int currel = 0;
                float racc = 0.f;

                for (int base = r0; base < r1; base += 64) {
                    int s = base + lane;
                    int pk = (s < r1) ? csr[s] : 0;
                    int src = pk & 0x1FFFF;
                    int rel = (pk >> 17) & 7;
                    float qq = __shfl(qv, rel, 64);
                    float tv = 0.f;
                    if (s < r1) {
                        float v = qq + kn[src * 8 + rel];
                        v = (v >= 0.f) ? v : 0.2f * v;
                        tv = __expf(v);
                    }
                    float ts = tv;
#pragma unroll
                    for (int off = 32; off > 0; off >>= 1) ts += __shfl_xor(ts, off, 64);
                    denom += ts;

                    int cnt = min(64, r1 - base);
                    int tvi = (int)__float_as_uint(tv);
                    for (int j = 0; j < cnt; j += 16) {
                        unsigned p[16];
                        float tf[16];
#pragma unroll
                        for (int u = 0; u < 16; u++) {
                            p[u] = (unsigned)__builtin_amdgcn_readlane(pk, j + u);
                            tf[u] = __uint_as_float(
                                (unsigned)__builtin_amdgcn_readlane(tvi, j + u));
                        }
                        unsigned xg[16];
#pragma unroll
                        for (int u = 0; u < 16; u++)
                            xg[u] = (unsigned)xb[(size_t)(p[u] & 0x1FFFF) * 64 + lane];
#pragma unroll
                        for (int u = 0; u < 16; u++) {
                            int rl = (int)((p[u] >> 17) & 7);
                            if (rl != currel) {
                                FLUSH8();
                                currel = rl;
                                racc = 0.f;
                            }
                            racc += tf[u] * __uint_as_float(xg[u] << 16);
                        }
                    }
                }
                FLUSH8();
                float inv = 1.f / (denom + 1e-16f);
                float av[8] = {a0, a1, a2, a3, a4, a5, a6, a7};
                unsigned short us[8];
#pragma unroll
                for (int r = 0; r < 8; r++) {
                    __hip_bfloat16 bb = __float2bfloat16(av[r] * inv);
                    us[r] = *(unsigned short*)&bb;
                }
                pack.x = (unsigned)us[0] | ((unsigned)us[1] << 16);
                pack.y = (unsigned)us[2] | ((unsigned)us[3] << 16);
                pack.z = (unsigned)us[4] | ((unsigned)us[5] << 16);
                pack.w = (unsigned)us[6] | ((unsigned)us[7] << 16);
            }
            *(uint4*)&zt[nl * ZSTR + lane * 8] = pack;
        }
    }
    __syncthreads();

    int quad = lane >> 4;
    int l15 = lane & 15;
    int nt = wv;
    if (nt * 16 < OUT) {
        const short* wh = (const short*)wthi;
        const short* wl = (const short*)wtlo;
        v4f acc = {0.f, 0.f, 0.f, 0.f};
#pragma unroll
        for (int k0 = 0; k0 < 512; k0 += 32) {
            int koff = k0 + quad * 8;
            v8s A = *(const v8s*)&zt[l15 * ZSTR + koff];
            v8s bh = *(const v8s*)(wh + (size_t)(nt * 16 + l15) * 512 + koff);
            v8s bl = *(const v8s*)(wl + (size_t)(nt * 16 + l15) * 512 + koff);
            acc = __builtin_amdgcn_mfma_f32_16x16x32_bf16(A, bh, acc, 0, 0, 0);
            acc = __builtin_amdgcn_mfma_f32_16x16x32_bf16(A, bl, acc, 0, 0, 0);
        }
        float bcol = bias[nt * 16 + l15];
#pragma unroll
        for (int g = 0; g < 4; g++) {
            int row = nb0 + quad * 4 + g;
            if (row < N) {
                float o = acc[g] + bcol;
                if (RELU) o = fmaxf(o, 0.f);
                xout[(size_t)row * OUT + nt * 16 + l15] = o;
            }
        }
    }
}

// ---------------- host launch ----------------

extern "C" void kernel_launch(void* const* d_in, const int* in_sizes, int n_in,
                              void* d_out, int out_size, void* d_ws, size_t ws_size,
                              hipStream_t stream) {
    const float* x   = (const float*)d_in[0];
    const int*   ei  = (const int*)d_in[1];
    const int*   et  = (const int*)d_in[2];
    const float* W0  = (const float*)d_in[3];
    const float* Q0  = (const float*)d_in[4];
    const float* K0  = (const float*)d_in[5];
    const float* b0  = (const float*)d_in[6];
    const float* W1  = (const float*)d_in[7];
    const float* Q1  = (const float*)d_in[8];
    const float* K1  = (const float*)d_in[9];
    const float* b1  = (const float*)d_in[10];
    float* out = (float*)d_out;

    const int N = in_sizes[0] / 64;
    const int E = in_sizes[2];
    const int* src = ei;
    const int* dst = ei + E;
    const int NB = (N + 255) >> 8;  // <= 512
    const int NS = (N + 7) / 8;     // slice width (nodes)

    char* p = (char*)d_ws;
    auto alloc = [&](size_t bytes) -> void* {
        void* r = (void*)p;
        p += ((bytes + 255) / 256) * 256;
        return r;
    };
    int* rp3      = (int*)alloc(((size_t)N + 1) * 8 * 4);
    int* bcount   = (int*)alloc(513 * 4);
    int* bstart   = (int*)alloc(513 * 4);
    int* gcur     = (int*)alloc(513 * 4);
    unsigned* ebuf = (unsigned*)alloc((size_t)E * 4);
    int* csr      = (int*)alloc((size_t)E * 4);
    float* wq     = (float*)alloc(8 * 64 * 4);
    float* wk     = (float*)alloc(8 * 64 * 4);
    float* qn     = (float*)alloc((size_t)N * 8 * 4);
    float* kn     = (float*)alloc((size_t)N * 8 * 4);
    __hip_bfloat16* wthi = (__hip_bfloat16*)alloc((size_t)64 * 512 * 2);
    __hip_bfloat16* wtlo = (__hip_bfloat16*)alloc((size_t)64 * 512 * 2);
    unsigned short* xbb = (unsigned short*)alloc((size_t)N * 64 * 2);
    // new-path extras (pout dominates); fallback's h aliases pout.
    char* psave = p;
    __half* pout = (__half*)alloc((size_t)8 * N * 64 * 2);
    float* pden  = (float*)alloc((size_t)8 * N * 4);
    size_t need_new = (size_t)(p - (char*)d_ws);
    p = psave;
    float* h = (float*)alloc((size_t)N * 64 * 4);  // fallback only
    bool newok = (need_new <= ws_size) && (NB <= 512);

    // --- CSR build (shared by both paths/layers) ---
    int nchunks = (E + CSR_CHUNK - 1) / CSR_CHUNK;
    hipMemsetAsync(bcount, 0, (size_t)NB * 4, stream);
    k_bhist<<<nchunks, 256, 0, stream>>>(dst, bcount, E, NB);
    k_bscan<<<1, 512, 0, stream>>>(bcount, bstart, gcur, rp3, NB, N, E);
    k_bscatter<<<nchunks, 256, 0, stream>>>(src, dst, et, gcur, ebuf, E, NB);
    k_bsort<<<NB, 256, 0, stream>>>(ebuf, bstart, rp3, csr, N, NS);

    int nfb = (N + 15) / 16;
    int nqkb = (N + 63) / 64;

    // --- layer-0 prep ---
    k_wqk<<<2, 256, 0, stream>>>(W0, Q0, K0, wq, wk, 64);
    k_qk2<<<nqkb, 256, 0, stream>>>(x, wq, wk, qn, kn, xbb, N);
    k_wt2<<<(8 * 64 * 64 + 255) / 256, 256, 0, stream>>>(W0, wthi, wtlo, 64, 8 * 64 * 64);

    if (newok) {
        // --- layer 0 ---
        k_agg<64><<<nfb * 8, 256, 0, stream>>>(rp3, csr, qn, kn, xbb,
                                               wthi, wtlo, pout, pden, N);
        k_wqk<<<2, 256, 0, stream>>>(W1, Q1, K1, wq, wk, 32);
        k_fin<64, true, true><<<nqkb, 256, 0, stream>>>(
            pout, pden, b0, wq, wk, qn, kn, xbb, nullptr, N);
        // --- layer 1 ---
        k_wt2<<<(8 * 64 * 32 + 255) / 256, 256, 0, stream>>>(W1, wthi, wtlo, 32,
                                                             8 * 64 * 32);
        k_agg<32><<<nfb * 8, 256, 0, stream>>>(rp3, csr, qn, kn, xbb,
                                               wthi, wtlo, pout, pden, N);
        k_fin<32, false, false><<<nqkb, 256, 0, stream>>>(
            pout, pden, b1, nullptr, nullptr, nullptr, nullptr, nullptr, out, N);
    } else {
        // --- fallback: R20 path ---
        k_fused<64, true><<<nfb, 256, 0, stream>>>(rp3, csr, qn, kn, xbb,
                                                   wthi, wtlo, b0, h, N);
        k_wqk<<<2, 256, 0, stream>>>(W1, Q1, K1, wq, wk, 32);
        k_qk2<<<nqkb, 256, 0, stream>>>(h, wq, wk, qn, kn, xbb, N);
        k_wt2<<<(8 * 64 * 32 + 255) / 256, 256, 0, stream>>>(W1, wthi, wtlo, 32,
                                                             8 * 64 * 32);
        k_fused<32, false><<<nfb, 256, 0, stream>>>(rp3, csr, qn, kn, xbb,
                                                    wthi, wtlo, b1, out, N);
    }
}

// Round 9
// 438.268 us; speedup vs baseline: 3.2054x; 3.2054x over previous
//
#include <hip/hip_runtime.h>
#include <hip/hip_bf16.h>
#include <math.h>

// ---------------- bucketed CSR build ----------------
// bucket = dst >> 8 (256 nodes/bucket). NB = ceil(N/256) <= 512.
// R6: single-pass random 4B scatter caused 16x write amplification -> two-level
// counting sort. R12: pass B sorts by 11-bit key (dstlocal*8 + rel) so each
// node's row is RELATION-SORTED -> run-length flushes in the agg loop.
// R22: this file is the exact R14 kernel (best harness-verified: 438.4us).
// R15-R21 post-mortems (all regressed or flat): the fused gather kernel is
// pinned at ~150us by the per-CU outstanding-miss cap (~16 lines) x ~650cy
// avg L3 latency ~= 1.45 TB/s ceiling; wave shape (R15), SW pipelining (R16),
// scalarized metadata (R17), message materialization (R18: ws-bound, and
// stream-traffic arithmetic is break-even), src-window sort (R19: temporal
// decoherence, FETCH unchanged), VALU trims (R20: flat -- not VALU-bound),
// XCD-slice pinning (R21: residency PROVEN, FETCH->0, but exchange costs
// -- 8x GEMM B-traffic + partial-out RMW -- exceed the gain) all fail to
// move it. This is the hardware floor for this access pattern.

#define CSR_CHUNK 8192

__global__ void k_bhist(const int* __restrict__ dst, int* __restrict__ bcount,
                        int E, int NB) {
    __shared__ int h[512];
    int t = threadIdx.x;
    for (int i = t; i < NB; i += 256) h[i] = 0;
    __syncthreads();
    int e0 = blockIdx.x * CSR_CHUNK;
    int e1 = min(e0 + CSR_CHUNK, E);
    for (int i = e0 + t; i < e1; i += 256) atomicAdd(&h[dst[i] >> 8], 1);
    __syncthreads();
    for (int i = t; i < NB; i += 256) {
        int c = h[i];
        if (c) atomicAdd(&bcount[i], c);
    }
}

__global__ void k_bscan(const int* __restrict__ bcount, int* __restrict__ bstart,
                        int* __restrict__ gcur, int* __restrict__ rowptr,
                        int NB, int N, int E) {
    __shared__ int s[512];
    int t = threadIdx.x;
    int v = (t < NB) ? bcount[t] : 0;
    s[t] = v;
    __syncthreads();
    for (int off = 1; off < 512; off <<= 1) {
        int a = (t >= off) ? s[t - off] : 0;
        __syncthreads();
        s[t] += a;
        __syncthreads();
    }
    int excl = s[t] - v;
    if (t < NB) {
        bstart[t] = excl;
        gcur[t] = excl;
    }
    if (t == 0) {
        bstart[NB] = E;
        rowptr[N] = E;
    }
}

// pass A: scatter packed edges grouped by bucket per block.
// pack: dstlocal(8) << 20 | rel(3) << 17 | src(17)
__global__ void k_bscatter(const int* __restrict__ src, const int* __restrict__ dst,
                           const int* __restrict__ et, int* __restrict__ gcur,
                           unsigned* __restrict__ ebuf, int E, int NB) {
    __shared__ int h[512];
    __shared__ int basearr[512];
    int t = threadIdx.x;
    for (int i = t; i < NB; i += 256) h[i] = 0;
    __syncthreads();
    int e0 = blockIdx.x * CSR_CHUNK;
    int e1 = min(e0 + CSR_CHUNK, E);
    for (int i = e0 + t; i < e1; i += 256) atomicAdd(&h[dst[i] >> 8], 1);
    __syncthreads();
    for (int i = t; i < NB; i += 256) {
        int c = h[i];
        basearr[i] = c ? atomicAdd(&gcur[i], c) : 0;
        h[i] = 0;
    }
    __syncthreads();
    for (int i = e0 + t; i < e1; i += 256) {
        int d = dst[i];
        int b = d >> 8;
        int off = atomicAdd(&h[b], 1);
        ebuf[basearr[b] + off] =
            ((unsigned)(d & 255) << 20) | ((unsigned)et[i] << 17) | (unsigned)src[i];
    }
}

// pass B: one block per bucket. 2048-bin (node,rel) counting sort -> rowptr
// (per node) + csr entries (rel<<17|src) sorted by (node, rel).
__global__ void k_bsort(const unsigned* __restrict__ ebuf, const int* __restrict__ bstart,
                        int* __restrict__ rowptr, int* __restrict__ csr, int N) {
    __shared__ int lh[2048];
    __shared__ int ls[2048];
    __shared__ int ss[256];
    int b = blockIdx.x, t = threadIdx.x;
    int e0 = bstart[b], e1 = bstart[b + 1];
    for (int i = t; i < 2048; i += 256) lh[i] = 0;
    __syncthreads();
    for (int i = e0 + t; i < e1; i += 256) {
        unsigned u = ebuf[i];
        atomicAdd(&lh[(int)(((u >> 20) & 255) * 8 + ((u >> 17) & 7))], 1);
    }
    __syncthreads();
    int loc[8];
    int s = 0;
#pragma unroll
    for (int j = 0; j < 8; j++) {
        loc[j] = s;
        s += lh[t * 8 + j];
    }
    ss[t] = s;
    __syncthreads();
    for (int off = 1; off < 256; off <<= 1) {
        int a = (t >= off) ? ss[t - off] : 0;
        __syncthreads();
        ss[t] += a;
        __syncthreads();
    }
    int excl = ss[t] - s;
#pragma unroll
    for (int j = 0; j < 8; j++) ls[t * 8 + j] = excl + loc[j];
    int node = b * 256 + t;
    if (node < N) rowptr[node] = e0 + excl;
    __syncthreads();
    for (int i = t; i < 2048; i += 256) lh[i] = 0;
    __syncthreads();
    for (int i = e0 + t; i < e1; i += 256) {
        unsigned u = ebuf[i];
        int key = (int)(((u >> 20) & 255) * 8 + ((u >> 17) & 7));
        int off = atomicAdd(&lh[key], 1);
        csr[e0 + ls[key] + off] = (int)(u & 0xFFFFF);
    }
}

// ---------------- weight prep ----------------

// Split-transpose into GEMM-B layout with K = i*8 + r (matches z layout):
// wt[o][i*8+r] = bf16(W[r][i][o]); lo = bf16 residual. K=512 rows total.
__global__ void k_wt2(const float* __restrict__ W, __hip_bfloat16* __restrict__ hi,
                      __hip_bfloat16* __restrict__ lo, int OUT, int total) {
    int t = blockIdx.x * blockDim.x + threadIdx.x;
    if (t < total) {
        int per = 64 * OUT;
        int r = t / per;
        int rem = t % per;
        int i = rem / OUT;
        int o = rem % OUT;
        float v = W[t];
        __hip_bfloat16 h = __float2bfloat16(v);
        __hip_bfloat16 l = __float2bfloat16(v - __bfloat162float(h));
        size_t idx = (size_t)o * 512 + i * 8 + r;
        hi[idx] = h;
        lo[idx] = l;
    }
}

// wq[r*64+i] = sum_o W[r,i,o]*Qv[o]; wk likewise. (fp32, tiny)
__global__ void k_wqk(const float* W, const float* Qv, const float* Kv,
                      float* wq, float* wk, int OUT) {
    int t = blockIdx.x * blockDim.x + threadIdx.x;
    if (t < 8 * 64) {
        int r = t >> 6, i = t & 63;
        const float* wrow = W + ((size_t)r * 64 + i) * OUT;
        float a = 0.f, b = 0.f;
        for (int o = 0; o < OUT; o++) {
            float w = wrow[o];
            a += w * Qv[o];
            b += w * Kv[o];
        }
        wq[t] = a;
        wk[t] = b;
    }
}

// ---------------- q/k projection + bf16 table emit ----------------
__global__ __launch_bounds__(256) void k_qk2(
        const float* __restrict__ xin, const float* __restrict__ wq,
        const float* __restrict__ wk, float* __restrict__ qn,
        float* __restrict__ kn, unsigned short* __restrict__ xbb, int N) {
    __shared__ float xt[64][65];
    __shared__ float swq[8 * 65], swk[8 * 65];
    int t = threadIdx.x;
    int nb0 = blockIdx.x * 64;
    for (int i = t; i < 512; i += 256) {
        int r = i >> 6, c = i & 63;
        swq[r * 65 + c] = wq[i];
        swk[r * 65 + c] = wk[i];
    }
    for (int i = t; i < 1024; i += 256) {
        int ns = i >> 4;   // 16 float4 per row
        int c4 = i & 15;
        int n = nb0 + ns;
        float4 v = {0.f, 0.f, 0.f, 0.f};
        if (n < N) v = ((const float4*)xin)[(size_t)n * 16 + c4];
        xt[ns][c4 * 4 + 0] = v.x;
        xt[ns][c4 * 4 + 1] = v.y;
        xt[ns][c4 * 4 + 2] = v.z;
        xt[ns][c4 * 4 + 3] = v.w;
        if (n < N) {
            __hip_bfloat16 b0 = __float2bfloat16(v.x);
            __hip_bfloat16 b1 = __float2bfloat16(v.y);
            __hip_bfloat16 b2 = __float2bfloat16(v.z);
            __hip_bfloat16 b3 = __float2bfloat16(v.w);
            ushort4 o;
            o.x = *(unsigned short*)&b0;
            o.y = *(unsigned short*)&b1;
            o.z = *(unsigned short*)&b2;
            o.w = *(unsigned short*)&b3;
            *(ushort4*)(xbb + (size_t)n * 64 + c4 * 4) = o;
        }
    }
    __syncthreads();
#pragma unroll
    for (int g = t; g < 512; g += 256) {
        int ns = g >> 3, r = g & 7;
        int n = nb0 + ns;
        if (n < N) {
            float qa = 0.f, ka = 0.f;
#pragma unroll
            for (int i = 0; i < 64; i++) {
                float xv = xt[ns][i];
                qa += xv * swq[r * 65 + i];
                ka += xv * swk[r * 65 + i];
            }
            qn[(size_t)n * 8 + r] = qa;
            kn[(size_t)n * 8 + r] = ka;
        }
    }
}

// ---------------- fused aggregation + transform (R14, best verified) ----------------
// Step 1 = block-wide EDGE-PARALLEL attention: 1 thread = 1 edge (coalesced
// csr, binsearch LDS rowptr for dst, LDS-staged q, 1 random kn gather, expf,
// LDS-atomic denom, 8B record {t,pk} to LDS) -> all ~256 kn gathers of the
// block in flight at once. Step 2 = per-wave drain from LDS records: 16
// broadcast ds_read_b64 -> readfirstlane (t,pk land in SGPRs) -> 16 saddr
// ushort gathers back-to-back -> rel-run-length FMA. Tail slots index-clamp
// to last real edge (L1-hot dup, weight 0). Oversized blocks (>EMAX edges;
// p~0 for Poisson(256)) use the per-wave node-serial path.
#define ZSTR 520
#define EMAX 512

#define FLUSH8()                          \
    do {                                  \
        switch (currel) {                 \
            case 0: a0 += racc; break;    \
            case 1: a1 += racc; break;    \
            case 2: a2 += racc; break;    \
            case 3: a3 += racc; break;    \
            case 4: a4 += racc; break;    \
            case 5: a5 += racc; break;    \
            case 6: a6 += racc; break;    \
            case 7: a7 += racc; break;    \
        }                                 \
    } while (0)

template <int OUT, bool RELU>
__global__ __launch_bounds__(256) void k_fused(
        const int* __restrict__ rowptr, const int* __restrict__ csr,
        const float* __restrict__ qn, const float* __restrict__ kn,
        const unsigned short* __restrict__ xb,
        const __hip_bfloat16* __restrict__ wthi,
        const __hip_bfloat16* __restrict__ wtlo,
        const float* __restrict__ bias, float* __restrict__ xout, int N) {
    using v8s = __attribute__((ext_vector_type(8))) short;
    using v4f = __attribute__((ext_vector_type(4))) float;
    __shared__ unsigned short zt[16 * ZSTR];
    __shared__ uint2 s_rec[EMAX];
    __shared__ int s_rp[17];
    __shared__ float s_q[128];
    __shared__ float s_den[16];
    int t = threadIdx.x;
    int wv = t >> 6;
    int lane = t & 63;
    int nb0 = blockIdx.x * 16;

    if (t < 17) {
        int nd = nb0 + t;
        s_rp[t] = rowptr[nd > N ? N : nd];
    }
    if (t < 128) {
        int nd = nb0 + (t >> 3);
        s_q[t] = (nd < N) ? qn[(size_t)nd * 8 + (t & 7)] : 0.f;
    }
    if (t < 16) s_den[t] = 0.f;
    __syncthreads();
    int e0 = s_rp[0];
    int esz = s_rp[16] - e0;

    if (esz <= EMAX) {
        // ---- step 1: edge-parallel attention, records to LDS ----
        for (int i = t; i < esz; i += 256) {
            int ge = e0 + i;
            int pk = csr[ge];
            int lo = 0;  // binary search: largest nl with s_rp[nl] <= ge
            lo = (s_rp[lo + 8] <= ge) ? lo + 8 : lo;
            lo = (s_rp[lo + 4] <= ge) ? lo + 4 : lo;
            lo = (s_rp[lo + 2] <= ge) ? lo + 2 : lo;
            lo = (s_rp[lo + 1] <= ge) ? lo + 1 : lo;
            int rel = pk >> 17;
            int src = pk & 0x1FFFF;
            float v = s_q[lo * 8 + rel] + kn[(size_t)src * 8 + rel];
            v = (v >= 0.f) ? v : 0.2f * v;
            float tv = __expf(v);
            atomicAdd(&s_den[lo], tv);
            s_rec[i] = uint2{__float_as_uint(tv), (unsigned)pk};
        }
        __syncthreads();

        // ---- step 2: per-wave gather+accumulate from LDS records ----
#pragma unroll 1
        for (int q = 0; q < 4; q++) {
            int nl = wv * 4 + q;
            int r0 = s_rp[nl] - e0;
            int r1 = s_rp[nl + 1] - e0;
            float a0 = 0.f, a1 = 0.f, a2 = 0.f, a3 = 0.f;
            float a4 = 0.f, a5 = 0.f, a6 = 0.f, a7 = 0.f;
            int currel = 0;
            float racc = 0.f;
#pragma unroll 1
            for (int j = r0; j < r1; j += 16) {
                float tvv[16];
                int pkk[16];
#pragma unroll
                for (int u = 0; u < 16; u++) {
                    int ii = j + u;
                    bool ok = ii < r1;
                    ii = ok ? ii : (r1 - 1);
                    uint2 rc = s_rec[ii];  // broadcast read (all lanes same addr)
                    tvv[u] = __uint_as_float(
                        __builtin_amdgcn_readfirstlane((int)(ok ? rc.x : 0u)));
                    pkk[u] = __builtin_amdgcn_readfirstlane((int)rc.y);
                }
                unsigned short xu[16];
#pragma unroll
                for (int u = 0; u < 16; u++)
                    xu[u] = xb[(size_t)(pkk[u] & 0x1FFFF) * 64 + lane];
#pragma unroll
                for (int u = 0; u < 16; u++) {
                    int rl = pkk[u] >> 17;  // SGPR
                    if (rl != currel) {     // uniform scalar branch
                        FLUSH8();
                        currel = rl;
                        racc = 0.f;
                    }
                    racc += tvv[u] * __uint_as_float(((unsigned)xu[u]) << 16);
                }
            }
            FLUSH8();
            float inv = 1.f / (s_den[nl] + 1e-16f);
            float av[8] = {a0, a1, a2, a3, a4, a5, a6, a7};
            unsigned short us[8];
#pragma unroll
            for (int r = 0; r < 8; r++) {
                __hip_bfloat16 b = __float2bfloat16(av[r] * inv);
                us[r] = *(unsigned short*)&b;
            }
            uint4 pack;
            pack.x = (unsigned)us[0] | ((unsigned)us[1] << 16);
            pack.y = (unsigned)us[2] | ((unsigned)us[3] << 16);
            pack.z = (unsigned)us[4] | ((unsigned)us[5] << 16);
            pack.w = (unsigned)us[6] | ((unsigned)us[7] << 16);
            *(uint4*)&zt[nl * ZSTR + lane * 8] = pack;
        }
    } else {
        // ---- fallback: per-wave node-serial path (rare: >EMAX edges) ----
        for (int q = 0; q < 4; q++) {
            int nl = wv * 4 + q;
            int wid = nb0 + nl;
            uint4 pack = {0u, 0u, 0u, 0u};
            if (wid < N) {
                int r0 = rowptr[wid], r1 = rowptr[wid + 1];
                float qv = (lane < 8) ? qn[wid * 8 + lane] : 0.f;
                float denom = 0.f;
                float a0 = 0.f, a1 = 0.f, a2 = 0.f, a3 = 0.f;
                float a4 = 0.f, a5 = 0.f, a6 = 0.f, a7 = 0.f;
                int currel = 0;
                float racc = 0.f;

                for (int base = r0; base < r1; base += 64) {
                    int s = base + lane;
                    int pk = (s < r1) ? csr[s] : 0;
                    int src = pk & 0x1FFFF;
                    int rel = pk >> 17;
                    float qq = __shfl(qv, rel, 64);
                    float tv = 0.f;
                    if (s < r1) {
                        float v = qq + kn[src * 8 + rel];
                        v = (v >= 0.f) ? v : 0.2f * v;
                        tv = __expf(v);
                    }
                    float ts = tv;
#pragma unroll
                    for (int off = 32; off > 0; off >>= 1) ts += __shfl_xor(ts, off, 64);
                    denom += ts;

                    int cnt = min(64, r1 - base);
                    int tvi = (int)__float_as_uint(tv);
                    for (int j = 0; j < cnt; j += 16) {
                        unsigned p[16];
                        float tf[16];
#pragma unroll
                        for (int u = 0; u < 16; u++) {
                            p[u] = (unsigned)__builtin_amdgcn_readlane(pk, j + u);
                            tf[u] = __uint_as_float(
                                (unsigned)__builtin_amdgcn_readlane(tvi, j + u));
                        }
                        unsigned xg[16];
#pragma unroll
                        for (int u = 0; u < 16; u++)
                            xg[u] = (unsigned)xb[(size_t)(p[u] & 0x1FFFF) * 64 + lane];
#pragma unroll
                        for (int u = 0; u < 16; u++) {
                            int rl = (int)(p[u] >> 17);
                            if (rl != currel) {
                                FLUSH8();
                                currel = rl;
                                racc = 0.f;
                            }
                            racc += tf[u] * __uint_as_float(xg[u] << 16);
                        }
                    }
                }
                FLUSH8();
                float inv = 1.f / (denom + 1e-16f);
                float av[8] = {a0, a1, a2, a3, a4, a5, a6, a7};
                unsigned short us[8];
#pragma unroll
                for (int r = 0; r < 8; r++) {
                    __hip_bfloat16 b = __float2bfloat16(av[r] * inv);
                    us[r] = *(unsigned short*)&b;
                }
                pack.x = (unsigned)us[0] | ((unsigned)us[1] << 16);
                pack.y = (unsigned)us[2] | ((unsigned)us[3] << 16);
                pack.z = (unsigned)us[4] | ((unsigned)us[5] << 16);
                pack.w = (unsigned)us[6] | ((unsigned)us[7] << 16);
            }
            *(uint4*)&zt[nl * ZSTR + lane * 8] = pack;
        }
    }
    __syncthreads();

    // ---- phase 2: out-tile GEMM from LDS ----
    int quad = lane >> 4;
    int l15 = lane & 15;
    int nt = wv;  // 16-col tile per wave
    if (nt * 16 < OUT) {
        const short* wh = (const short*)wthi;
        const short* wl = (const short*)wtlo;
        v4f acc = {0.f, 0.f, 0.f, 0.f};
#pragma unroll
        for (int k0 = 0; k0 < 512; k0 += 32) {
            int koff = k0 + quad * 8;
            v8s A = *(const v8s*)&zt[l15 * ZSTR + koff];
            v8s bh = *(const v8s*)(wh + (size_t)(nt * 16 + l15) * 512 + koff);
            v8s bl = *(const v8s*)(wl + (size_t)(nt * 16 + l15) * 512 + koff);
            acc = __builtin_amdgcn_mfma_f32_16x16x32_bf16(A, bh, acc, 0, 0, 0);
            acc = __builtin_amdgcn_mfma_f32_16x16x32_bf16(A, bl, acc, 0, 0, 0);
        }
        float bcol = bias[nt * 16 + l15];
#pragma unroll
        for (int g = 0; g < 4; g++) {
            int row = nb0 + quad * 4 + g;
            if (row < N) {
                float o = acc[g] + bcol;
                if (RELU) o = fmaxf(o, 0.f);
                xout[(size_t)row * OUT + nt * 16 + l15] = o;
            }
        }
    }
}

// ---------------- host launch ----------------

extern "C" void kernel_launch(void* const* d_in, const int* in_sizes, int n_in,
                              void* d_out, int out_size, void* d_ws, size_t ws_size,
                              hipStream_t stream) {
    const float* x   = (const float*)d_in[0];
    const int*   ei  = (const int*)d_in[1];
    const int*   et  = (const int*)d_in[2];
    const float* W0  = (const float*)d_in[3];
    const float* Q0  = (const float*)d_in[4];
    const float* K0  = (const float*)d_in[5];
    const float* b0  = (const float*)d_in[6];
    const float* W1  = (const float*)d_in[7];
    const float* Q1  = (const float*)d_in[8];
    const float* K1  = (const float*)d_in[9];
    const float* b1  = (const float*)d_in[10];
    float* out = (float*)d_out;

    const int N = in_sizes[0] / 64;
    const int E = in_sizes[2];
    const int* src = ei;
    const int* dst = ei + E;
    const int NB = (N + 255) >> 8;  // <= 512

    char* p = (char*)d_ws;
    auto alloc = [&](size_t bytes) -> void* {
        void* r = (void*)p;
        p += ((bytes + 255) / 256) * 256;
        return r;
    };
    int* rowptr   = (int*)alloc((size_t)(N + 1) * 4);
    int* bcount   = (int*)alloc(513 * 4);
    int* bstart   = (int*)alloc(513 * 4);
    int* gcur     = (int*)alloc(513 * 4);
    unsigned* ebuf = (unsigned*)alloc((size_t)E * 4);
    int* csr      = (int*)alloc((size_t)E * 4);
    float* wq     = (float*)alloc(8 * 64 * 4);
    float* wk     = (float*)alloc(8 * 64 * 4);
    float* qn     = (float*)alloc((size_t)N * 8 * 4);
    float* kn     = (float*)alloc((size_t)N * 8 * 4);
    __hip_bfloat16* wthi = (__hip_bfloat16*)alloc((size_t)64 * 512 * 2);
    __hip_bfloat16* wtlo = (__hip_bfloat16*)alloc((size_t)64 * 512 * 2);
    float* h      = (float*)alloc((size_t)N * 64 * 4);
    unsigned short* xbb = (unsigned short*)alloc((size_t)N * 64 * 2);  // bf16 gather table

    // --- CSR build (bucketed counting sort; shared by both layers) ---
    int nchunks = (E + CSR_CHUNK - 1) / CSR_CHUNK;
    hipMemsetAsync(bcount, 0, (size_t)NB * 4, stream);
    k_bhist<<<nchunks, 256, 0, stream>>>(dst, bcount, E, NB);
    k_bscan<<<1, 512, 0, stream>>>(bcount, bstart, gcur, rowptr, NB, N, E);
    k_bscatter<<<nchunks, 256, 0, stream>>>(src, dst, et, gcur, ebuf, E, NB);
    k_bsort<<<NB, 256, 0, stream>>>(ebuf, bstart, rowptr, csr, N);

    int nfb = (N + 15) / 16;
    int nqkb = (N + 63) / 64;

    // --- layer 0: 64 -> 64, relu ---
    k_wqk<<<2, 256, 0, stream>>>(W0, Q0, K0, wq, wk, 64);
    k_qk2<<<nqkb, 256, 0, stream>>>(x, wq, wk, qn, kn, xbb, N);
    k_wt2<<<(8 * 64 * 64 + 255) / 256, 256, 0, stream>>>(W0, wthi, wtlo, 64, 8 * 64 * 64);
    k_fused<64, true><<<nfb, 256, 0, stream>>>(rowptr, csr, qn, kn, xbb,
                                               wthi, wtlo, b0, h, N);

    // --- layer 1: 64 -> 32, no relu ---
    k_wqk<<<2, 256, 0, stream>>>(W1, Q1, K1, wq, wk, 32);
    k_qk2<<<nqkb, 256, 0, stream>>>(h, wq, wk, qn, kn, xbb, N);
    k_wt2<<<(8 * 64 * 32 + 255) / 256, 256, 0, stream>>>(W1, wthi, wtlo, 32, 8 * 64 * 32);
    k_fused<32, false><<<nfb, 256, 0, stream>>>(rowptr, csr, qn, kn, xbb,
                                                wthi, wtlo, b1, out, N);
}